// Round 9
// baseline (1026.672 us; speedup 1.0000x reference)
//
#include <hip/hip_runtime.h>
#include <math.h>

typedef short  bf16x8 __attribute__((ext_vector_type(8)));
typedef float  f32x4  __attribute__((ext_vector_type(4)));
typedef float  f32x2  __attribute__((ext_vector_type(2)));

#define DIM   1024
#define RANK  256
#define NROWS 16
#define NT    512
#define NWAVE 8
#define TOTAL_ROWS 4096
#define OUT_HALF (TOTAL_ROWS*DIM)

// LDS byte layout
#define VS_OFF   0            // ushort[16][1024], XOR-swizzled rows (32768)
#define H2_OFF   32768        // ushort[16][256],  XOR-swizzled rows (8192)
#define GS_OFF   40960        // ushort[16][1032]  pitch 2064 B (33024)
#define GS_PITCH 2064
#define XS_OFF   73984        // float[16][1024] thread-private x state (65536)
#define WS_OFF   139520       // float[16][8] (512)
#define SG_OFF   140032       // float[16]    (64)
#define SMEM_BYTES 140096     // 1 block/CU guaranteed (2x > 160K)

static constexpr double XI  = 0.1786178958448091;
static constexpr double LAM = -0.2123418310626054;
static constexpr double CHI = -0.0662645826698185;

__device__ __forceinline__ unsigned short f2bf(float f) {
    unsigned u = __builtin_bit_cast(unsigned, f);
    u += 0x7FFFu + ((u >> 16) & 1u);        // round-to-nearest-even
    return (unsigned short)(u >> 16);
}
__device__ __forceinline__ float bf2f(unsigned short b) {
    return __builtin_bit_cast(float, ((unsigned)b) << 16);
}

// swizzle: byte ^= (row&7)<<4 -> 16 A-rows spread over 8 16B slots
__device__ __forceinline__ int vs_addr(int m, int kb) {
    return VS_OFF + ((m * 2048 + kb) ^ ((m & 7) << 4));
}
__device__ __forceinline__ int h2_addr(int m, int kb) {
    return H2_OFF + ((m * 512 + kb) ^ ((m & 7) << 4));
}

// ---- prep: pack U,W (fp32) into bf16 MFMA B-fragment order in d_ws ----
// B-frag 16x16x32: lane l holds B[k = kt*32 + (l>>4)*8 + j][n = nt*16 + (l&15)]
// U slot = kt*16+nt (kt<32,nt<16); W slot = 512 + kt*64+nt (kt<8,nt<64)
__global__ __launch_bounds__(256)
void prep_pack(const float* __restrict__ U, const float* __restrict__ Wm,
               bf16x8* __restrict__ pk)
{
    const int tid  = blockIdx.x * 256 + threadIdx.x;   // 0..65535
    const int lane = tid & 63;
    const int frag = tid >> 6;                          // 0..1023
    bf16x8 o;
    if (frag < 512) {
        const int kt = frag >> 4, nt = frag & 15;
        const int krow = kt * 32 + (lane >> 4) * 8;
        const int n    = nt * 16 + (lane & 15);
        #pragma unroll
        for (int j = 0; j < 8; ++j) o[j] = (short)f2bf(U[(krow + j) * RANK + n]);
    } else {
        const int f = frag - 512;
        const int kt = f >> 6, nt = f & 63;
        const int krow = kt * 32 + (lane >> 4) * 8;
        const int n    = nt * 16 + (lane & 15);
        #pragma unroll
        for (int j = 0; j < 8; ++j) o[j] = (short)f2bf(Wm[(krow + j) * DIM + n]);
    }
    pk[frag * 64 + lane] = o;
}

// Register budget engineered under the 128-VGPR allocation hipcc picks for
// 512-thread blocks (R3/R6/R7 evidence): x state lives in LDS (thread-
// private slots), force is re-read from L2 in the kick, rings are 8x1-frag.
__global__ __launch_bounds__(NT)
void omelyan_mfma(const float* __restrict__ x_in,
                  const float* __restrict__ v_in,
                  const float* __restrict__ force,
                  const float* __restrict__ Vw,
                  const int* __restrict__ steps_p,
                  const bf16x8* __restrict__ pk,
                  float* __restrict__ out)
{
    extern __shared__ char smem[];
    float* wsums = (float*)(smem + WS_OFF);
    float* sings = (float*)(smem + SG_OFF);
    float* xsp   = (float*)(smem + XS_OFF);   // [16][1024] f32, thread-private

    const int t    = threadIdx.x;        // 0..511
    const int lane = t & 63;
    const int w    = t >> 6;             // 0..7
    const int row0 = blockIdx.x * NROWS;
    const int nsteps = steps_p[0];

    const float dt = 0.01f;

    // per-thread register state: ONLY v (elements d = 2t+j, j=0,1)
    float vr[NROWS][2];
    const f32x2 vw = *(const f32x2*)&Vw[2 * t];

    #pragma unroll
    for (int m = 0; m < NROWS; ++m) {
        const int base = (row0 + m) * DIM + 2 * t;
        const f32x2 xv = *(const f32x2*)&x_in[base];
        const f32x2 vv = *(const f32x2*)&v_in[base];
        vr[m][0] = vv[0]; vr[m][1] = vv[1];
        *(f32x2*)&xsp[m * 1024 + 2 * t] = xv;
        const unsigned p = (unsigned)f2bf(vv[0]) | ((unsigned)f2bf(vv[1]) << 16);
        *(unsigned*)(smem + vs_addr(m, 4 * t)) = p;
    }
    __syncthreads();

    #pragma unroll 1
    for (int step = 0; step < nsteps; ++step) {
        #pragma unroll 1
        for (int sub = 0; sub < 4; ++sub) {
            const float cdt = dt * (sub == 0 ? (float)XI :
                                    sub == 1 ? (float)CHI :
                                    sub == 2 ? (float)(1.0 - 2.0 * (CHI + XI)) :
                                               (float)CHI);
            const float ddt = dt * ((sub == 0 || sub == 3)
                                    ? (float)((1.0 - 2.0 * LAM) * 0.5)
                                    : (float)LAM);

            // ---- drift x (LDS RMW, thread-private) + r2 partial ----
            #pragma unroll
            for (int m = 0; m < NROWS; ++m) {
                f32x2 x2 = *(f32x2*)&xsp[m * 1024 + 2 * t];
                x2[0] = fmaf(cdt, vr[m][0], x2[0]);
                x2[1] = fmaf(cdt, vr[m][1], x2[1]);
                *(f32x2*)&xsp[m * 1024 + 2 * t] = x2;
                float s = fmaf(x2[0], x2[0], x2[1] * x2[1]);
                #pragma unroll
                for (int off = 32; off >= 1; off >>= 1) s += __shfl_xor(s, off, 64);
                if (lane == 0) wsums[m * NWAVE + w] = s;
            }

            // ---- H: h = v @ U (M=16,N=256,K=1024); wave owns 2 n-tiles ----
            // flat micro-stream u = ks*2 + i (64 micros), ring-8 x 1 frag
            {
                f32x4 hacc0 = {0.f,0.f,0.f,0.f}, hacc1 = {0.f,0.f,0.f,0.f};
                bf16x8 bb[8];
                #pragma unroll
                for (int u = 0; u < 8; ++u)
                    bb[u] = pk[((u >> 1) * 16 + w * 2 + (u & 1)) * 64 + lane];
                bf16x8 areg[2];
                areg[0] = *(const bf16x8*)(smem + vs_addr(lane & 15, (lane >> 4) * 16));
                #pragma unroll
                for (int ks = 0; ks < 32; ++ks) {
                    if (ks + 1 < 32)
                        areg[(ks + 1) & 1] = *(const bf16x8*)(smem + vs_addr(lane & 15, (ks + 1) * 64 + (lane >> 4) * 16));
                    const int u0 = 2 * ks, u1 = 2 * ks + 1;
                    hacc0 = __builtin_amdgcn_mfma_f32_16x16x32_bf16(areg[ks & 1], bb[u0 & 7], hacc0, 0, 0, 0);
                    if (u0 + 8 < 64)
                        bb[u0 & 7] = pk[(((u0 + 8) >> 1) * 16 + w * 2 + ((u0 + 8) & 1)) * 64 + lane];
                    hacc1 = __builtin_amdgcn_mfma_f32_16x16x32_bf16(areg[ks & 1], bb[u1 & 7], hacc1, 0, 0, 0);
                    if (u1 + 8 < 64)
                        bb[u1 & 7] = pk[(((u1 + 8) >> 1) * 16 + w * 2 + ((u1 + 8) & 1)) * 64 + lane];
                }
                // h2 = (h*h) bf16, swizzled; D: col=lane&15, row=(lane>>4)*4+r
                #pragma unroll
                for (int r = 0; r < 4; ++r) {
                    const int m  = (lane >> 4) * 4 + r;
                    const int n0 = (w * 2 + 0) * 16 + (lane & 15);
                    const int n1 = (w * 2 + 1) * 16 + (lane & 15);
                    *(unsigned short*)(smem + h2_addr(m, 2 * n0)) = f2bf(hacc0[r] * hacc0[r]);
                    *(unsigned short*)(smem + h2_addr(m, 2 * n1)) = f2bf(hacc1[r] * hacc1[r]);
                }
            }
            __syncthreads();                            // b2 (covers wsums + h2)

            if (t < NROWS) {
                float r2 = 0.f;
                #pragma unroll
                for (int q = 0; q < NWAVE; ++q) r2 += wsums[t * NWAVE + q];
                sings[t] = 1.f + exp2f(-r2 * 1.4426950408889634f);
            }

            // ---- G: gamma = h2 @ W (M=16,N=1024,K=256); 8 passes x 1 n-tile ----
            // flat micro-stream u = pass*8 + kk, ring-8 x 1 frag
            {
                bf16x8 wb[8];
                #pragma unroll
                for (int u = 0; u < 8; ++u)
                    wb[u] = pk[(512 + (u & 7) * 64 + w * 8 + 0) * 64 + lane];
                #pragma unroll
                for (int pass = 0; pass < 8; ++pass) {
                    f32x4 g = {0.f, 0.f, 0.f, 0.f};
                    bf16x8 areg[2];
                    areg[0] = *(const bf16x8*)(smem + h2_addr(lane & 15, (lane >> 4) * 16));
                    #pragma unroll
                    for (int kk = 0; kk < 8; ++kk) {
                        if (kk + 1 < 8)
                            areg[(kk + 1) & 1] = *(const bf16x8*)(smem + h2_addr(lane & 15, (kk + 1) * 64 + (lane >> 4) * 16));
                        g = __builtin_amdgcn_mfma_f32_16x16x32_bf16(areg[kk & 1], wb[(pass * 8 + kk) & 7], g, 0, 0, 0);
                        const int u8 = pass * 8 + kk + 8;
                        if (u8 < 64)
                            wb[(pass * 8 + kk) & 7] = pk[(512 + (u8 & 7) * 64 + w * 8 + (u8 >> 3)) * 64 + lane];
                    }
                    // gs (bf16): col = (w*8+pass)*16 + (lane&15), row = (lane>>4)*4+r
                    #pragma unroll
                    for (int r = 0; r < 4; ++r) {
                        const int m  = (lane >> 4) * 4 + r;
                        const int cb = (w * 8 + pass) * 16 + (lane & 15);
                        *(unsigned short*)(smem + GS_OFF + m * GS_PITCH + cb * 2) = f2bf(g[r]);
                    }
                }
            }
            __syncthreads();                            // b3 (covers gs + sings)

            // ---- kick: v += ddt*(force - gamma*gate*sing); refresh vs ----
            // force re-read from global (L2-resident); x re-read from LDS
            #pragma unroll
            for (int m = 0; m < NROWS; ++m) {
                const f32x2 fm = *(const f32x2*)&force[(row0 + m) * DIM + 2 * t];
                const f32x2 x2 = *(const f32x2*)&xsp[m * 1024 + 2 * t];
                const unsigned gu = *(const unsigned*)(smem + GS_OFF + m * GS_PITCH + 4 * t);
                const float gL = bf2f((unsigned short)(gu & 0xFFFFu));
                const float gH = bf2f((unsigned short)(gu >> 16));
                const float sing = sings[m];
                unsigned pp = 0;
                #pragma unroll
                for (int j = 0; j < 2; ++j) {
                    const float g  = j ? gH : gL;
                    const float z  = x2[j] * vw[j];
                    const float e  = exp2f(z * 2.885390081777927f);   // e^(2z)
                    const float th = 1.f - 2.f / (e + 1.f);           // tanh(z)
                    const float gate = fmaf(0.1f, th, 1.f);
                    const float a = fm[j] - g * gate * sing;
                    vr[m][j] = fmaf(ddt, a, vr[m][j]);
                    pp |= ((unsigned)f2bf(vr[m][j])) << (16 * j);
                }
                *(unsigned*)(smem + vs_addr(m, 4 * t)) = pp;
            }
            __syncthreads();                            // b4 (vs ready for next H)
        } // sub

        // final drift: x += C5*dt*v  (LDS RMW, thread-private)
        const float c5dt = dt * (float)XI;
        #pragma unroll
        for (int m = 0; m < NROWS; ++m) {
            f32x2 x2 = *(f32x2*)&xsp[m * 1024 + 2 * t];
            x2[0] = fmaf(c5dt, vr[m][0], x2[0]);
            x2[1] = fmaf(c5dt, vr[m][1], x2[1]);
            *(f32x2*)&xsp[m * 1024 + 2 * t] = x2;
        }
    } // step

    // ---- store (x, v) ----
    #pragma unroll
    for (int m = 0; m < NROWS; ++m) {
        const int base = (row0 + m) * DIM + 2 * t;
        const f32x2 x2 = *(const f32x2*)&xsp[m * 1024 + 2 * t];
        f32x2 vo; vo[0] = vr[m][0]; vo[1] = vr[m][1];
        *(f32x2*)&out[base] = x2;
        *(f32x2*)&out[OUT_HALF + base] = vo;
    }
}

extern "C" void kernel_launch(void* const* d_in, const int* in_sizes, int n_in,
                              void* d_out, int out_size, void* d_ws, size_t ws_size,
                              hipStream_t stream) {
    const float* x_in  = (const float*)d_in[0];
    const float* v_in  = (const float*)d_in[1];
    const float* force = (const float*)d_in[2];
    const float* Umat  = (const float*)d_in[3];
    const float* Wmat  = (const float*)d_in[4];
    const float* Vw    = (const float*)d_in[5];
    const int*   steps = (const int*)d_in[6];
    float* out = (float*)d_out;
    bf16x8* pk = (bf16x8*)d_ws;   // 1 MiB

    (void)hipFuncSetAttribute((const void*)omelyan_mfma,
                              hipFuncAttributeMaxDynamicSharedMemorySize,
                              SMEM_BYTES);

    prep_pack<<<dim3(256), dim3(256), 0, stream>>>(Umat, Wmat, pk);
    omelyan_mfma<<<dim3(TOTAL_ROWS / NROWS), dim3(NT), SMEM_BYTES, stream>>>(
        x_in, v_in, force, Vw, steps, pk, out);
}

// Round 10
// 959.911 us; speedup vs baseline: 1.0695x; 1.0695x over previous
//
#include <hip/hip_runtime.h>
#include <math.h>

typedef short  bf16x8 __attribute__((ext_vector_type(8)));
typedef float  f32x4  __attribute__((ext_vector_type(4)));
typedef unsigned short us4 __attribute__((ext_vector_type(4)));

#define DIM   1024
#define RANK  256
#define NROWS 16
#define NT    256
#define NWAVE 4
#define TOTAL_ROWS 4096
#define OUT_HALF (TOTAL_ROWS*DIM)

// LDS byte layout
#define VS_OFF   0            // ushort[16][1024], XOR-swizzled rows (32768)
#define H2_OFF   32768        // ushort[16][256],  XOR-swizzled rows (8192)
#define GS_OFF   40960        // ushort[16][1032]  pitch 2064 B (33024)
#define GS_PITCH 2064
#define WS_OFF   73984        // float[16][4] (256)
#define SG_OFF   74240        // float[16]    (64)
#define SMEM_BYTES 74304

static constexpr double XI  = 0.1786178958448091;
static constexpr double LAM = -0.2123418310626054;
static constexpr double CHI = -0.0662645826698185;

__device__ __forceinline__ unsigned short f2bf(float f) {
    unsigned u = __builtin_bit_cast(unsigned, f);
    u += 0x7FFFu + ((u >> 16) & 1u);        // round-to-nearest-even
    return (unsigned short)(u >> 16);
}
__device__ __forceinline__ float bf2f(unsigned short b) {
    return __builtin_bit_cast(float, ((unsigned)b) << 16);
}

// swizzle: byte ^= (row&7)<<4 -> 16 A-rows spread over 8 16B slots
__device__ __forceinline__ int vs_addr(int m, int kb) {
    return VS_OFF + ((m * 2048 + kb) ^ ((m & 7) << 4));
}
__device__ __forceinline__ int h2_addr(int m, int kb) {
    return H2_OFF + ((m * 512 + kb) ^ ((m & 7) << 4));
}

// ---- prep: pack U,W (fp32) into bf16 MFMA B-fragment order in d_ws ----
// B-frag 16x16x32: lane l holds B[k = kt*32 + (l>>4)*8 + j][n = nt*16 + (l&15)]
// U slot = kt*16+nt (kt<32,nt<16); W slot = 512 + kt*64+nt (kt<8,nt<64)
__global__ __launch_bounds__(256)
void prep_pack(const float* __restrict__ U, const float* __restrict__ Wm,
               bf16x8* __restrict__ pk)
{
    const int tid  = blockIdx.x * 256 + threadIdx.x;   // 0..65535
    const int lane = tid & 63;
    const int frag = tid >> 6;                          // 0..1023
    bf16x8 o;
    if (frag < 512) {
        const int kt = frag >> 4, nt = frag & 15;
        const int krow = kt * 32 + (lane >> 4) * 8;
        const int n    = nt * 16 + (lane & 15);
        #pragma unroll
        for (int j = 0; j < 8; ++j) o[j] = (short)f2bf(U[(krow + j) * RANK + n]);
    } else {
        const int f = frag - 512;
        const int kt = f >> 6, nt = f & 63;
        const int krow = kt * 32 + (lane >> 4) * 8;
        const int n    = nt * 16 + (lane & 15);
        #pragma unroll
        for (int j = 0; j < 8; ++j) o[j] = (short)f2bf(Wm[(krow + j) * DIM + n]);
    }
    pk[frag * 64 + lane] = o;
}

// 256-thread block: the ONLY shape where the allocator grants a ~256-VGPR
// budget (R1: 208, R2: 256; 512-thr is always pinned to 128, 1024-thr to 64).
// Demand engineered to ~210: state 132 (x,v,vw; no force copy), ring 32,
// areg 8, accs 16, temps.
__global__ __launch_bounds__(NT, 1)
void omelyan_mfma(const float* __restrict__ x_in,
                  const float* __restrict__ v_in,
                  const float* __restrict__ force,
                  const float* __restrict__ Vw,
                  const int* __restrict__ steps_p,
                  const bf16x8* __restrict__ pk,
                  float* __restrict__ out)
{
    extern __shared__ char smem[];
    float* wsums = (float*)(smem + WS_OFF);
    float* sings = (float*)(smem + SG_OFF);

    const int t    = threadIdx.x;        // 0..255
    const int lane = t & 63;
    const int w    = t >> 6;             // 0..3
    const int row0 = blockIdx.x * NROWS;
    const int nsteps = steps_p[0];

    const float dt = 0.01f;

    // per-thread elementwise state: elements (m, d = 4t+j), j=0..3
    f32x4 xr[NROWS], vr[NROWS];
    const f32x4 vw = *(const f32x4*)&Vw[4 * t];

    #pragma unroll
    for (int m = 0; m < NROWS; ++m) {
        const int base = (row0 + m) * DIM + 4 * t;
        xr[m] = *(const f32x4*)&x_in[base];
        const f32x4 vv = *(const f32x4*)&v_in[base];
        vr[m] = vv;
        us4 p;
        #pragma unroll
        for (int j = 0; j < 4; ++j) p[j] = f2bf(vv[j]);
        *(us4*)(smem + vs_addr(m, 8 * t)) = p;
    }
    __syncthreads();

    #pragma unroll 1
    for (int step = 0; step < nsteps; ++step) {
        #pragma unroll 1
        for (int sub = 0; sub < 4; ++sub) {
            const float cdt = dt * (sub == 0 ? (float)XI :
                                    sub == 1 ? (float)CHI :
                                    sub == 2 ? (float)(1.0 - 2.0 * (CHI + XI)) :
                                               (float)CHI);
            const float ddt = dt * ((sub == 0 || sub == 3)
                                    ? (float)((1.0 - 2.0 * LAM) * 0.5)
                                    : (float)LAM);

            // ---- H ring prologue: micros 0..7 (frag(u) = (u>>2)*16 + w*4 + (u&3))
            // pk is barrier-independent: these overlap the drift VALU below.
            bf16x8 bb[8];
            #pragma unroll
            for (int u = 0; u < 8; ++u)
                bb[u] = pk[((u >> 2) * 16 + w * 4 + (u & 3)) * 64 + lane];

            // ---- drift x + r2 partial (barrier folded into b2) ----
            #pragma unroll
            for (int m = 0; m < NROWS; ++m) {
                f32x4 x2 = xr[m];
                float s = 0.f;
                #pragma unroll
                for (int j = 0; j < 4; ++j) {
                    x2[j] = fmaf(cdt, vr[m][j], x2[j]);
                    s = fmaf(x2[j], x2[j], s);
                }
                xr[m] = x2;
                #pragma unroll
                for (int off = 32; off >= 1; off >>= 1) s += __shfl_xor(s, off, 64);
                if (lane == 0) wsums[m * NWAVE + w] = s;
            }

            // ---- H: h = v @ U (M=16,N=256,K=1024); wave owns 4 n-tiles ----
            {
                f32x4 h0 = {0.f,0.f,0.f,0.f}, h1 = {0.f,0.f,0.f,0.f};
                f32x4 h2v = {0.f,0.f,0.f,0.f}, h3 = {0.f,0.f,0.f,0.f};
                bf16x8 areg[2];
                areg[0] = *(const bf16x8*)(smem + vs_addr(lane & 15, (lane >> 4) * 16));
                #pragma unroll
                for (int ks = 0; ks < 32; ++ks) {
                    if (ks + 1 < 32)
                        areg[(ks + 1) & 1] = *(const bf16x8*)(smem + vs_addr(lane & 15, (ks + 1) * 64 + (lane >> 4) * 16));
                    #pragma unroll
                    for (int i = 0; i < 4; ++i) {
                        const int u = ks * 4 + i;
                        f32x4 acc = (i == 0) ? h0 : (i == 1) ? h1 : (i == 2) ? h2v : h3;
                        acc = __builtin_amdgcn_mfma_f32_16x16x32_bf16(areg[ks & 1], bb[u & 7], acc, 0, 0, 0);
                        if (i == 0) h0 = acc; else if (i == 1) h1 = acc; else if (i == 2) h2v = acc; else h3 = acc;
                        if (u + 8 < 128)
                            bb[u & 7] = pk[(((u + 8) >> 2) * 16 + w * 4 + ((u + 8) & 3)) * 64 + lane];
                    }
                }
                // h2 = (h*h) bf16, swizzled; D: col=lane&15, row=(lane>>4)*4+r
                #pragma unroll
                for (int r = 0; r < 4; ++r) {
                    const int m = (lane >> 4) * 4 + r;
                    const int c = lane & 15;
                    *(unsigned short*)(smem + h2_addr(m, 2 * ((w * 4 + 0) * 16 + c))) = f2bf(h0[r] * h0[r]);
                    *(unsigned short*)(smem + h2_addr(m, 2 * ((w * 4 + 1) * 16 + c))) = f2bf(h1[r] * h1[r]);
                    *(unsigned short*)(smem + h2_addr(m, 2 * ((w * 4 + 2) * 16 + c))) = f2bf(h2v[r] * h2v[r]);
                    *(unsigned short*)(smem + h2_addr(m, 2 * ((w * 4 + 3) * 16 + c))) = f2bf(h3[r] * h3[r]);
                }
            }
            __syncthreads();                            // b2 (covers wsums + h2)

            if (t < NROWS) {
                float r2 = 0.f;
                #pragma unroll
                for (int q = 0; q < NWAVE; ++q) r2 += wsums[t * NWAVE + q];
                sings[t] = 1.f + exp2f(-r2 * 1.4426950408889634f);
            }

            // ---- G: gamma = h2 @ W (M=16,N=1024,K=256); 4 passes x 4 n-tiles ----
            {
                bf16x8 wb[8];
                // ring prologue: micros 0..7 of pass 0 (u = kk*4+i)
                #pragma unroll
                for (int u = 0; u < 8; ++u)
                    wb[u] = pk[512 * 64 + (((u >> 2) * 64) + w * 16 + 0 * 4 + (u & 3)) * 64 + lane];
                #pragma unroll 1
                for (int pass = 0; pass < 4; ++pass) {
                    f32x4 g0 = {0.f,0.f,0.f,0.f}, g1 = {0.f,0.f,0.f,0.f};
                    f32x4 g2 = {0.f,0.f,0.f,0.f}, g3 = {0.f,0.f,0.f,0.f};
                    bf16x8 areg[2];
                    areg[0] = *(const bf16x8*)(smem + h2_addr(lane & 15, (lane >> 4) * 16));
                    #pragma unroll
                    for (int kk = 0; kk < 8; ++kk) {
                        if (kk + 1 < 8)
                            areg[(kk + 1) & 1] = *(const bf16x8*)(smem + h2_addr(lane & 15, (kk + 1) * 64 + (lane >> 4) * 16));
                        #pragma unroll
                        for (int i = 0; i < 4; ++i) {
                            const int u = kk * 4 + i;
                            f32x4 acc = (i == 0) ? g0 : (i == 1) ? g1 : (i == 2) ? g2 : g3;
                            acc = __builtin_amdgcn_mfma_f32_16x16x32_bf16(areg[kk & 1], wb[u & 7], acc, 0, 0, 0);
                            if (i == 0) g0 = acc; else if (i == 1) g1 = acc; else if (i == 2) g2 = acc; else g3 = acc;
                            // prefetch micro u+8 (may cross into next pass)
                            const int u2 = u + 8;
                            if (u2 < 32) {
                                wb[u & 7] = pk[512 * 64 + (((u2 >> 2) * 64) + w * 16 + pass * 4 + (u2 & 3)) * 64 + lane];
                            } else if (pass < 3) {
                                const int v2 = u2 - 32;
                                wb[u & 7] = pk[512 * 64 + (((v2 >> 2) * 64) + w * 16 + (pass + 1) * 4 + (v2 & 3)) * 64 + lane];
                            }
                        }
                    }
                    // gs (bf16): col = (w*16 + pass*4 + i)*16 + (lane&15)
                    #pragma unroll
                    for (int r = 0; r < 4; ++r) {
                        const int m = (lane >> 4) * 4 + r;
                        const int c = lane & 15;
                        const int cb = (w * 16 + pass * 4) * 16 + c;
                        *(unsigned short*)(smem + GS_OFF + m * GS_PITCH + (cb +  0) * 2) = f2bf(g0[r]);
                        *(unsigned short*)(smem + GS_OFF + m * GS_PITCH + (cb + 16) * 2) = f2bf(g1[r]);
                        *(unsigned short*)(smem + GS_OFF + m * GS_PITCH + (cb + 32) * 2) = f2bf(g2[r]);
                        *(unsigned short*)(smem + GS_OFF + m * GS_PITCH + (cb + 48) * 2) = f2bf(g3[r]);
                    }
                }
            }
            __syncthreads();                            // b3 (covers gs + sings)

            // ---- kick: v += ddt*(force - gamma*gate*sing); refresh vs ----
            // force re-read from global (L2-resident): saves 64 VGPRs of state
            #pragma unroll
            for (int m = 0; m < NROWS; ++m) {
                const f32x4 fm = *(const f32x4*)&force[(row0 + m) * DIM + 4 * t];
                const unsigned gu0 = *(const unsigned*)(smem + GS_OFF + m * GS_PITCH + 8 * t);
                const unsigned gu1 = *(const unsigned*)(smem + GS_OFF + m * GS_PITCH + 8 * t + 4);
                const float gv[4] = { bf2f((unsigned short)(gu0 & 0xFFFFu)),
                                      bf2f((unsigned short)(gu0 >> 16)),
                                      bf2f((unsigned short)(gu1 & 0xFFFFu)),
                                      bf2f((unsigned short)(gu1 >> 16)) };
                const float sing = sings[m];
                f32x4 vv = vr[m];
                us4 pp;
                #pragma unroll
                for (int j = 0; j < 4; ++j) {
                    const float z  = xr[m][j] * vw[j];
                    const float e  = exp2f(z * 2.885390081777927f);   // e^(2z)
                    const float th = 1.f - 2.f / (e + 1.f);           // tanh(z)
                    const float gate = fmaf(0.1f, th, 1.f);
                    const float a = fm[j] - gv[j] * gate * sing;
                    vv[j] = fmaf(ddt, a, vv[j]);
                    pp[j] = f2bf(vv[j]);
                }
                vr[m] = vv;
                *(us4*)(smem + vs_addr(m, 8 * t)) = pp;
            }
            __syncthreads();                            // b4 (vs ready for next H)
        } // sub

        // final drift: x += C5*dt*v
        const float c5dt = dt * (float)XI;
        #pragma unroll
        for (int m = 0; m < NROWS; ++m) {
            f32x4 x2 = xr[m];
            #pragma unroll
            for (int j = 0; j < 4; ++j) x2[j] = fmaf(c5dt, vr[m][j], x2[j]);
            xr[m] = x2;
        }
    } // step

    // ---- store (x, v) ----
    #pragma unroll
    for (int m = 0; m < NROWS; ++m) {
        const int base = (row0 + m) * DIM + 4 * t;
        *(f32x4*)&out[base] = xr[m];
        *(f32x4*)&out[OUT_HALF + base] = vr[m];
    }
}

extern "C" void kernel_launch(void* const* d_in, const int* in_sizes, int n_in,
                              void* d_out, int out_size, void* d_ws, size_t ws_size,
                              hipStream_t stream) {
    const float* x_in  = (const float*)d_in[0];
    const float* v_in  = (const float*)d_in[1];
    const float* force = (const float*)d_in[2];
    const float* Umat  = (const float*)d_in[3];
    const float* Wmat  = (const float*)d_in[4];
    const float* Vw    = (const float*)d_in[5];
    const int*   steps = (const int*)d_in[6];
    float* out = (float*)d_out;
    bf16x8* pk = (bf16x8*)d_ws;   // 1 MiB

    (void)hipFuncSetAttribute((const void*)omelyan_mfma,
                              hipFuncAttributeMaxDynamicSharedMemorySize,
                              SMEM_BYTES);

    prep_pack<<<dim3(256), dim3(256), 0, stream>>>(Umat, Wmat, pk);
    omelyan_mfma<<<dim3(TOTAL_ROWS / NROWS), dim3(NT), SMEM_BYTES, stream>>>(
        x_in, v_in, force, Vw, steps, pk, out);
}

// Round 11
// 504.983 us; speedup vs baseline: 2.0331x; 1.9009x over previous
//
#include <hip/hip_runtime.h>
#include <math.h>

typedef short  bf16x8 __attribute__((ext_vector_type(8)));
typedef float  f32x4  __attribute__((ext_vector_type(4)));
typedef float  f32x2  __attribute__((ext_vector_type(2)));

#define DIM   1024
#define RANK  256
#define NROWS 16
#define NT    512
#define NWAVE 8
#define TOTAL_ROWS 4096
#define OUT_HALF (TOTAL_ROWS*DIM)

// LDS byte layout
#define VS_OFF    0           // ushort[16][1024] swizzled: v (H input) / gamma (G out) / v' (kick)
#define H2_OFF    32768       // ushort[16][256] swizzled
#define STAGE_OFF 40960       // 4 slots x 16 KB staging ring (65536)
#define SLOTS     4
#define WS_OFF    106496      // float[16][8]
#define SG_OFF    107008      // float[16]
#define SMEM_BYTES 107072

static constexpr double XI  = 0.1786178958448091;
static constexpr double LAM = -0.2123418310626054;
static constexpr double CHI = -0.0662645826698185;

typedef __attribute__((address_space(1))) void as1_void;
typedef __attribute__((address_space(3))) void as3_void;

#define WAITV(n) asm volatile("s_waitcnt vmcnt(" #n ")" ::: "memory")

// batch barrier: LDS ops drained, global_load_lds stream stays in flight
__device__ __forceinline__ void bbar() {
    asm volatile("s_waitcnt lgkmcnt(0)" ::: "memory");
    __builtin_amdgcn_s_barrier();
}

__device__ __forceinline__ unsigned short f2bf(float f) {
    unsigned u = __builtin_bit_cast(unsigned, f);
    u += 0x7FFFu + ((u >> 16) & 1u);        // round-to-nearest-even
    return (unsigned short)(u >> 16);
}
__device__ __forceinline__ float bf2f(unsigned short b) {
    return __builtin_bit_cast(float, ((unsigned)b) << 16);
}

// swizzle: byte ^= (row&7)<<4
__device__ __forceinline__ int vs_addr(int m, int kb) {
    return VS_OFF + ((m * 2048 + kb) ^ ((m & 7) << 4));
}
__device__ __forceinline__ int h2_addr(int m, int kb) {
    return H2_OFF + ((m * 512 + kb) ^ ((m & 7) << 4));
}

// issue this wave's 2 frags (positions 2w, 2w+1) of stream batch sb into the ring
__device__ __forceinline__ void issue2(const char* pkb, char* smem_, int sb, int w, int lane) {
    char* dst = smem_ + STAGE_OFF + (sb & (SLOTS - 1)) * 16384 + (2 * w) * 1024;
    const char* g = pkb + (size_t)(((unsigned)(sb * 16 + 2 * w)) << 10) + lane * 16;
    __builtin_amdgcn_global_load_lds((const as1_void*)g,          (as3_void*)dst,          16, 0, 0);
    __builtin_amdgcn_global_load_lds((const as1_void*)(g + 1024), (as3_void*)(dst + 1024), 16, 0, 0);
}

// ---- prep: pack U,W into the bf16 consumption-order STREAM (64 batches x 16 KB).
// Batch b<32 (H, ks=b): frag j = U-fragment(kt=b, nt=j).
// Batch 32+idx (G): region=idx>>4 (pass A/B), ga=idx&15, kk=ga>>1, p=ga&1;
//   frag j (w'=j>>1, i=j&1) = W-fragment(kt=kk, nt = 8w' + 4*region + 2p + i).
// B-frag 16x16x32: lane l holds B[k = kt*32 + (l>>4)*8 + jj][n = nt*16 + (l&15)]
__global__ __launch_bounds__(256)
void prep_pack(const float* __restrict__ U, const float* __restrict__ Wm,
               bf16x8* __restrict__ pk)
{
    const int tid  = blockIdx.x * 256 + threadIdx.x;   // 0..65535
    const int lane = tid & 63;
    const int frag = tid >> 6;                          // 0..1023
    bf16x8 o;
    if (frag < 512) {
        const int kt = frag >> 4, nt = frag & 15;
        const int krow = kt * 32 + (lane >> 4) * 8;
        const int n    = nt * 16 + (lane & 15);
        #pragma unroll
        for (int j = 0; j < 8; ++j) o[j] = (short)f2bf(U[(krow + j) * RANK + n]);
    } else {
        const int idx = frag - 512;                     // 0..511
        const int b   = idx >> 4;                       // 0..31
        const int j   = idx & 15;
        const int region = b >> 4;                      // 0 = pass A, 1 = pass B
        const int ga  = b & 15;
        const int kk  = ga >> 1, p = ga & 1;
        const int wv  = j >> 1, i = j & 1;
        const int nt  = wv * 8 + region * 4 + p * 2 + i;
        const int krow = kk * 32 + (lane >> 4) * 8;
        const int n    = nt * 16 + (lane & 15);
        #pragma unroll
        for (int jj = 0; jj < 8; ++jj) o[jj] = (short)f2bf(Wm[(krow + jj) * DIM + n]);
    }
    pk[frag * 64 + lane] = o;
}

__global__ __launch_bounds__(NT)
void omelyan_mfma(const float* __restrict__ x_in,
                  const float* __restrict__ v_in,
                  const float* __restrict__ force,
                  const float* __restrict__ Vw,
                  const int* __restrict__ steps_p,
                  const bf16x8* __restrict__ pk,
                  float* __restrict__ out)
{
    extern __shared__ char smem[];
    float* wsums = (float*)(smem + WS_OFF);
    float* sings = (float*)(smem + SG_OFF);
    const char* pkb = (const char*)pk;

    const int t    = threadIdx.x;        // 0..511
    const int lane = t & 63;
    const int w    = t >> 6;             // 0..7
    const int row0 = blockIdx.x * NROWS;
    const int nsteps = steps_p[0];

    const float dt = 0.01f;

    // per-thread state: elements (m, d = 2t+j), j=0,1
    float xr[NROWS][2], vr[NROWS][2];
    const f32x2 vw = *(const f32x2*)&Vw[2 * t];

    #pragma unroll
    for (int m = 0; m < NROWS; ++m) {
        const int base = (row0 + m) * DIM + 2 * t;
        const f32x2 xv = *(const f32x2*)&x_in[base];
        const f32x2 vv = *(const f32x2*)&v_in[base];
        xr[m][0] = xv[0]; xr[m][1] = xv[1];
        vr[m][0] = vv[0]; vr[m][1] = vv[1];
        const unsigned p = (unsigned)f2bf(vv[0]) | ((unsigned)f2bf(vv[1]) << 16);
        *(unsigned*)(smem + vs_addr(m, 4 * t)) = p;
    }
    __syncthreads();    // clean vmcnt base

    // prime the stream: batches 0,1,2 (6 loads/wave in flight)
    issue2(pkb, smem, 0, w, lane);
    issue2(pkb, smem, 1, w, lane);
    issue2(pkb, smem, 2, w, lane);

    #pragma unroll 1
    for (int step = 0; step < nsteps; ++step) {
        #pragma unroll 1
        for (int sub = 0; sub < 4; ++sub) {
            const float cdt = dt * (sub == 0 ? (float)XI :
                                    sub == 1 ? (float)CHI :
                                    sub == 2 ? (float)(1.0 - 2.0 * (CHI + XI)) :
                                               (float)CHI);
            const float ddt = dt * ((sub == 0 || sub == 3)
                                    ? (float)((1.0 - 2.0 * LAM) * 0.5)
                                    : (float)LAM);

            // ---- drift x + r2 reduce -> wsums ----
            #pragma unroll
            for (int m = 0; m < NROWS; ++m) {
                float s = 0.f;
                #pragma unroll
                for (int j = 0; j < 2; ++j) {
                    xr[m][j] = fmaf(cdt, vr[m][j], xr[m][j]);
                    s = fmaf(xr[m][j], xr[m][j], s);
                }
                #pragma unroll
                for (int off = 32; off >= 1; off >>= 1) s += __shfl_xor(s, off, 64);
                if (lane == 0) wsums[m * NWAVE + w] = s;
            }
            bbar();                         // wsums + prior kick's vs visible
            if (t < NROWS) {
                float r2 = 0.f;
                #pragma unroll
                for (int q = 0; q < NWAVE; ++q) r2 += wsums[t * NWAVE + q];
                sings[t] = 1.f + exp2f(-r2 * 1.4426950408889634f);
            }

            // ---- H: batches 0..31 (wave consumes nt 2w, 2w+1) ----
            f32x4 h0 = {0.f,0.f,0.f,0.f}, h1 = {0.f,0.f,0.f,0.f};
            #pragma unroll 4
            for (int ks = 0; ks < 32; ++ks) {
                bbar();
                WAITV(4);                    // own loads for batch ks retired
                const bf16x8 a  = *(const bf16x8*)(smem + vs_addr(lane & 15, ks * 64 + (lane >> 4) * 16));
                const char* sp = smem + STAGE_OFF + (ks & 3) * 16384 + (2 * w) * 1024 + lane * 16;
                const bf16x8 f0 = *(const bf16x8*)sp;
                const bf16x8 f1 = *(const bf16x8*)(sp + 1024);
                h0 = __builtin_amdgcn_mfma_f32_16x16x32_bf16(a, f0, h0, 0, 0, 0);
                h1 = __builtin_amdgcn_mfma_f32_16x16x32_bf16(a, f1, h1, 0, 0, 0);
                issue2(pkb, smem, (ks + 3) & 63, w, lane);   // prefetch depth 3
            }
            // h2 = h*h (bf16, swizzled); D: col=lane&15, row=(lane>>4)*4+r
            #pragma unroll
            for (int r = 0; r < 4; ++r) {
                const int m = (lane >> 4) * 4 + r;
                const int c = lane & 15;
                *(unsigned short*)(smem + h2_addr(m, 2 * ((2 * w + 0) * 16 + c))) = f2bf(h0[r] * h0[r]);
                *(unsigned short*)(smem + h2_addr(m, 2 * ((2 * w + 1) * 16 + c))) = f2bf(h1[r] * h1[r]);
            }

            // ---- G pass A: batches 32..47 (wave accumulates nt 8w..8w+3) ----
            {
                f32x4 g0 = {0.f,0.f,0.f,0.f}, g1 = {0.f,0.f,0.f,0.f};
                f32x4 g2 = {0.f,0.f,0.f,0.f}, g3 = {0.f,0.f,0.f,0.f};
                #pragma unroll
                for (int kk = 0; kk < 8; ++kk) {
                    #pragma unroll
                    for (int p = 0; p < 2; ++p) {
                        const int b = 32 + kk * 2 + p;
                        bbar();
                        WAITV(4);
                        const bf16x8 a = *(const bf16x8*)(smem + h2_addr(lane & 15, kk * 64 + (lane >> 4) * 16));
                        const char* sp = smem + STAGE_OFF + (b & 3) * 16384 + (2 * w) * 1024 + lane * 16;
                        const bf16x8 f0 = *(const bf16x8*)sp;
                        const bf16x8 f1 = *(const bf16x8*)(sp + 1024);
                        if (p == 0) {
                            g0 = __builtin_amdgcn_mfma_f32_16x16x32_bf16(a, f0, g0, 0, 0, 0);
                            g1 = __builtin_amdgcn_mfma_f32_16x16x32_bf16(a, f1, g1, 0, 0, 0);
                        } else {
                            g2 = __builtin_amdgcn_mfma_f32_16x16x32_bf16(a, f0, g2, 0, 0, 0);
                            g3 = __builtin_amdgcn_mfma_f32_16x16x32_bf16(a, f1, g3, 0, 0, 0);
                        }
                        issue2(pkb, smem, (b + 3) & 63, w, lane);
                    }
                }
                // gamma (bf16) into the dead vs region, same swizzled cells
                #pragma unroll
                for (int r = 0; r < 4; ++r) {
                    const int m = (lane >> 4) * 4 + r;
                    const int c = lane & 15;
                    *(unsigned short*)(smem + vs_addr(m, 2 * ((8 * w + 0) * 16 + c))) = f2bf(g0[r]);
                    *(unsigned short*)(smem + vs_addr(m, 2 * ((8 * w + 1) * 16 + c))) = f2bf(g1[r]);
                    *(unsigned short*)(smem + vs_addr(m, 2 * ((8 * w + 2) * 16 + c))) = f2bf(g2[r]);
                    *(unsigned short*)(smem + vs_addr(m, 2 * ((8 * w + 3) * 16 + c))) = f2bf(g3[r]);
                }
            }

            // ---- G pass B: batches 48..63 (nt 8w+4..8w+7) ----
            {
                f32x4 g0 = {0.f,0.f,0.f,0.f}, g1 = {0.f,0.f,0.f,0.f};
                f32x4 g2 = {0.f,0.f,0.f,0.f}, g3 = {0.f,0.f,0.f,0.f};
                #pragma unroll
                for (int kk = 0; kk < 8; ++kk) {
                    #pragma unroll
                    for (int p = 0; p < 2; ++p) {
                        const int b = 48 + kk * 2 + p;
                        bbar();
                        WAITV(4);
                        const bf16x8 a = *(const bf16x8*)(smem + h2_addr(lane & 15, kk * 64 + (lane >> 4) * 16));
                        const char* sp = smem + STAGE_OFF + (b & 3) * 16384 + (2 * w) * 1024 + lane * 16;
                        const bf16x8 f0 = *(const bf16x8*)sp;
                        const bf16x8 f1 = *(const bf16x8*)(sp + 1024);
                        if (p == 0) {
                            g0 = __builtin_amdgcn_mfma_f32_16x16x32_bf16(a, f0, g0, 0, 0, 0);
                            g1 = __builtin_amdgcn_mfma_f32_16x16x32_bf16(a, f1, g1, 0, 0, 0);
                        } else {
                            g2 = __builtin_amdgcn_mfma_f32_16x16x32_bf16(a, f0, g2, 0, 0, 0);
                            g3 = __builtin_amdgcn_mfma_f32_16x16x32_bf16(a, f1, g3, 0, 0, 0);
                        }
                        issue2(pkb, smem, (b + 3) & 63, w, lane);  // wraps to next accel's 0..2
                    }
                }
                #pragma unroll
                for (int r = 0; r < 4; ++r) {
                    const int m = (lane >> 4) * 4 + r;
                    const int c = lane & 15;
                    *(unsigned short*)(smem + vs_addr(m, 2 * ((8 * w + 4) * 16 + c))) = f2bf(g0[r]);
                    *(unsigned short*)(smem + vs_addr(m, 2 * ((8 * w + 5) * 16 + c))) = f2bf(g1[r]);
                    *(unsigned short*)(smem + vs_addr(m, 2 * ((8 * w + 6) * 16 + c))) = f2bf(g2[r]);
                    *(unsigned short*)(smem + vs_addr(m, 2 * ((8 * w + 7) * 16 + c))) = f2bf(g3[r]);
                }
            }
            bbar();                                     // gamma visible

            // ---- kick: read gamma from vs cells, write v' back to same cells ----
            #pragma unroll
            for (int m = 0; m < NROWS; ++m) {
                const f32x2 fm = *(const f32x2*)&force[(row0 + m) * DIM + 2 * t];
                const unsigned gu = *(const unsigned*)(smem + vs_addr(m, 4 * t));
                const float gL = bf2f((unsigned short)(gu & 0xFFFFu));
                const float gH = bf2f((unsigned short)(gu >> 16));
                const float sing = sings[m];
                unsigned pp = 0;
                #pragma unroll
                for (int j = 0; j < 2; ++j) {
                    const float g  = j ? gH : gL;
                    const float z  = xr[m][j] * vw[j];
                    const float e  = exp2f(z * 2.885390081777927f);   // e^(2z)
                    const float th = 1.f - 2.f / (e + 1.f);           // tanh(z)
                    const float gate = fmaf(0.1f, th, 1.f);
                    const float a = fm[j] - g * gate * sing;
                    vr[m][j] = fmaf(ddt, a, vr[m][j]);
                    pp |= ((unsigned)f2bf(vr[m][j])) << (16 * j);
                }
                *(unsigned*)(smem + vs_addr(m, 4 * t)) = pp;   // same-thread RMW
            }
            // next accel's first bbar() covers these vs writes
        } // sub

        // final drift: x += C5*dt*v
        const float c5dt = dt * (float)XI;
        #pragma unroll
        for (int m = 0; m < NROWS; ++m)
            #pragma unroll
            for (int j = 0; j < 2; ++j)
                xr[m][j] = fmaf(c5dt, vr[m][j], xr[m][j]);
    } // step

    __syncthreads();    // drain dangling prefetches before exit/store

    // ---- store (x, v) ----
    #pragma unroll
    for (int m = 0; m < NROWS; ++m) {
        const int base = (row0 + m) * DIM + 2 * t;
        f32x2 xo, vo;
        xo[0] = xr[m][0]; xo[1] = xr[m][1];
        vo[0] = vr[m][0]; vo[1] = vr[m][1];
        *(f32x2*)&out[base] = xo;
        *(f32x2*)&out[OUT_HALF + base] = vo;
    }
}

extern "C" void kernel_launch(void* const* d_in, const int* in_sizes, int n_in,
                              void* d_out, int out_size, void* d_ws, size_t ws_size,
                              hipStream_t stream) {
    const float* x_in  = (const float*)d_in[0];
    const float* v_in  = (const float*)d_in[1];
    const float* force = (const float*)d_in[2];
    const float* Umat  = (const float*)d_in[3];
    const float* Wmat  = (const float*)d_in[4];
    const float* Vw    = (const float*)d_in[5];
    const int*   steps = (const int*)d_in[6];
    float* out = (float*)d_out;
    bf16x8* pk = (bf16x8*)d_ws;   // 1 MiB stream

    (void)hipFuncSetAttribute((const void*)omelyan_mfma,
                              hipFuncAttributeMaxDynamicSharedMemorySize,
                              SMEM_BYTES);

    prep_pack<<<dim3(256), dim3(256), 0, stream>>>(Umat, Wmat, pk);
    omelyan_mfma<<<dim3(TOTAL_ROWS / NROWS), dim3(NT), SMEM_BYTES, stream>>>(
        x_in, v_in, force, Vw, steps, pk, out);
}